// Round 1
// baseline (408.299 us; speedup 1.0000x reference)
//
#include <hip/hip_runtime.h>
#include <hip/hip_bf16.h>

// Problem constants
#define B_ 4
#define T_ 2048
#define C_ 1024
#define H_ 16
#define D_ 64

typedef __attribute__((ext_vector_type(8))) short bf16x8;
typedef __attribute__((ext_vector_type(4))) short short4v;
typedef __attribute__((ext_vector_type(4))) float f32x4;

static __device__ __forceinline__ short f2bf(float f) {
    union { float f; unsigned u; } v; v.f = f;
    unsigned r = v.u + 0x7fffu + ((v.u >> 16) & 1u);
    return (short)(r >> 16);
}

// ---------------------------------------------------------------------------
// Pack wq/wk/wv [H][C][D] fp32 -> wqkv_t [N=3072][K=1024] bf16 (B^T layout)
// n = qkv*1024 + h*64 + d
// ---------------------------------------------------------------------------
__global__ void pack_wqkv(const float* __restrict__ wq, const float* __restrict__ wk,
                          const float* __restrict__ wv, short* __restrict__ out) {
    int tid = blockIdx.x * blockDim.x + threadIdx.x;  // 3072*128 threads
    int n  = tid >> 7;
    int kc = tid & 127;
    int qkv = n >> 10;
    int h = (n >> 6) & 15;
    int d = n & 63;
    const float* w = (qkv == 0) ? wq : (qkv == 1) ? wk : wv;
    const float* src = w + (size_t)h * (C_ * D_) + d;
    short* dst = out + (size_t)n * C_ + kc * 8;
#pragma unroll
    for (int j = 0; j < 8; ++j)
        dst[j] = f2bf(src[(size_t)(kc * 8 + j) * D_]);
}

// w_proj [C][C] fp32 -> wproj_t [N=1024][K=1024] bf16
__global__ void pack_wproj(const float* __restrict__ wp, short* __restrict__ out) {
    int tid = blockIdx.x * blockDim.x + threadIdx.x;  // 1024*128 threads
    int n  = tid >> 7;
    int kc = tid & 127;
    short* dst = out + (size_t)n * C_ + kc * 8;
#pragma unroll
    for (int j = 0; j < 8; ++j)
        dst[j] = f2bf(wp[(size_t)(kc * 8 + j) * C_ + n]);
}

// ---------------------------------------------------------------------------
// GEMM: C[M][N] = A[M][K] x B[K][N], B given transposed as Bt[N][K] bf16.
// A fp32 (converted on load) or bf16. Output bf16 or fp32(+bias).
// 128x128 tile, BK=32, 4 waves (2x2), mfma_f32_16x16x32_bf16.
// ---------------------------------------------------------------------------
template<bool A_F32, bool OUT_F32>
__global__ __launch_bounds__(256)
void gemm_bf16(const void* __restrict__ Aptr, const short* __restrict__ Bt,
               void* __restrict__ Cptr, const float* __restrict__ bias,
               int M, int N, int K) {
    __shared__ short As[128][40];  // [m][k], +8 pad
    __shared__ short Bs[128][40];  // [n][k], +8 pad

    const int tid = threadIdx.x;
    const int lane = tid & 63;
    const int wid = tid >> 6;
    const int wr = wid >> 1, wc = wid & 1;
    const int l15 = lane & 15, l4 = lane >> 4;
    const int m0 = blockIdx.y * 128;
    const int n0 = blockIdx.x * 128;

    f32x4 acc[4][4] = {};

    for (int k0 = 0; k0 < K; k0 += 32) {
        // ---- stage A tile (128 x 32) ----
        if (A_F32) {
            const float* A = (const float*)Aptr;
#pragma unroll
            for (int i = 0; i < 4; ++i) {
                int e = tid + i * 256;
                int r = e >> 3, cv = e & 7;
                float4 v = *(const float4*)(A + (size_t)(m0 + r) * K + k0 + cv * 4);
                short4v s;
                s[0] = f2bf(v.x); s[1] = f2bf(v.y); s[2] = f2bf(v.z); s[3] = f2bf(v.w);
                *(short4v*)&As[r][cv * 4] = s;
            }
        } else {
            const short* A = (const short*)Aptr;
#pragma unroll
            for (int i = 0; i < 2; ++i) {
                int e = tid + i * 256;
                int r = e >> 2, cv = e & 3;
                bf16x8 v = *(const bf16x8*)(A + (size_t)(m0 + r) * K + k0 + cv * 8);
                *(bf16x8*)&As[r][cv * 8] = v;
            }
        }
        // ---- stage B tile (128 x 32 of Bt) ----
#pragma unroll
        for (int i = 0; i < 2; ++i) {
            int e = tid + i * 256;
            int r = e >> 2, cv = e & 3;
            bf16x8 v = *(const bf16x8*)(Bt + (size_t)(n0 + r) * K + k0 + cv * 8);
            *(bf16x8*)&Bs[r][cv * 8] = v;
        }
        __syncthreads();

        bf16x8 af[4], bf[4];
#pragma unroll
        for (int m = 0; m < 4; ++m)
            af[m] = *(const bf16x8*)&As[wr * 64 + m * 16 + l15][l4 * 8];
#pragma unroll
        for (int n = 0; n < 4; ++n)
            bf[n] = *(const bf16x8*)&Bs[wc * 64 + n * 16 + l15][l4 * 8];
#pragma unroll
        for (int m = 0; m < 4; ++m)
#pragma unroll
            for (int n = 0; n < 4; ++n)
                acc[m][n] = __builtin_amdgcn_mfma_f32_16x16x32_bf16(af[m], bf[n], acc[m][n], 0, 0, 0);
        __syncthreads();
    }

    // ---- epilogue: D layout row=(lane>>4)*4+r, col=lane&15 ----
#pragma unroll
    for (int m = 0; m < 4; ++m) {
        int row_base = m0 + wr * 64 + m * 16 + l4 * 4;
#pragma unroll
        for (int n = 0; n < 4; ++n) {
            int col = n0 + wc * 64 + n * 16 + l15;
#pragma unroll
            for (int r = 0; r < 4; ++r) {
                int row = row_base + r;
                float v = acc[m][n][r];
                if (OUT_F32) {
                    ((float*)Cptr)[(size_t)row * N + col] = v + (bias ? bias[col] : 0.0f);
                } else {
                    ((short*)Cptr)[(size_t)row * N + col] = f2bf(v);
                }
            }
        }
    }
}

// ---------------------------------------------------------------------------
// Flash attention, causal. qkv: [B*T][3072] bf16 (Q|K|V per head inside).
// out: [B*T][1024] bf16 (heads concatenated). One block = 64 q-rows of one
// (b,h); 4 waves x 16 rows; KV tiles of 64.
// ---------------------------------------------------------------------------
__global__ __launch_bounds__(256)
void attn_kernel(const short* __restrict__ qkv, short* __restrict__ out) {
    const int qt = blockIdx.x;        // 0..31
    const int bh = blockIdx.y;        // 0..63
    const int b = bh >> 4;
    const int h = bh & 15;
    const int q0 = qt * 64;
    const int tid = threadIdx.x;
    const int wave = tid >> 6;
    const int lane = tid & 63;
    const int l15 = lane & 15, l4 = lane >> 4;

    __shared__ short Qs[64][72];
    __shared__ short Ks[64][72];
    __shared__ short Vt[64][72];        // Vt[d][s]
    __shared__ short Ps[4][16][72];     // per-wave P buffer

    const size_t rs = 3 * C_;  // 3072
    const short* qbase = qkv + ((size_t)b * T_ + q0) * rs + h * 64;
    const short* kbase = qkv + (size_t)b * T_ * rs + C_ + h * 64;
    const short* vbase = qkv + (size_t)b * T_ * rs + 2 * C_ + h * 64;

    // stage Q tile once
#pragma unroll
    for (int i = 0; i < 2; ++i) {
        int e = tid + i * 256;
        int r = e >> 3, dc = e & 7;
        bf16x8 v = *(const bf16x8*)(qbase + (size_t)r * rs + dc * 8);
        *(bf16x8*)&Qs[r][dc * 8] = v;
    }
    __syncthreads();
    bf16x8 aq[2];
    aq[0] = *(const bf16x8*)&Qs[wave * 16 + l15][l4 * 8];
    aq[1] = *(const bf16x8*)&Qs[wave * 16 + l15][32 + l4 * 8];

    f32x4 O[4] = {};
    float mrow[4], srow[4];
#pragma unroll
    for (int r = 0; r < 4; ++r) { mrow[r] = -1e30f; srow[r] = 0.0f; }

    for (int s0 = 0; s0 <= q0; s0 += 64) {
        __syncthreads();  // protect Ks/Vt from previous iteration's readers
        // stage K tile
#pragma unroll
        for (int i = 0; i < 2; ++i) {
            int e = tid + i * 256;
            int r = e >> 3, dc = e & 7;
            bf16x8 v = *(const bf16x8*)(kbase + (size_t)(s0 + r) * rs + dc * 8);
            *(bf16x8*)&Ks[r][dc * 8] = v;
        }
        // stage V transposed: Vt[d][s]
#pragma unroll
        for (int i = 0; i < 2; ++i) {
            int e = tid + i * 256;
            int d = e & 63, sc = e >> 6;
            bf16x8 v;
#pragma unroll
            for (int j = 0; j < 8; ++j)
                v[j] = vbase[(size_t)(s0 + sc * 8 + j) * rs + d];
            *(bf16x8*)&Vt[d][sc * 8] = v;
        }
        __syncthreads();

        // ---- S = Q K^T (per wave: 16x64) ----
        f32x4 S[4];
#pragma unroll
        for (int n = 0; n < 4; ++n) {
            bf16x8 bk0 = *(const bf16x8*)&Ks[n * 16 + l15][l4 * 8];
            bf16x8 bk1 = *(const bf16x8*)&Ks[n * 16 + l15][32 + l4 * 8];
            f32x4 z = {};
            z = __builtin_amdgcn_mfma_f32_16x16x32_bf16(aq[0], bk0, z, 0, 0, 0);
            S[n] = __builtin_amdgcn_mfma_f32_16x16x32_bf16(aq[1], bk1, z, 0, 0, 0);
        }

        // ---- scale + causal mask + row max ----
        const int qrow = q0 + wave * 16 + l4 * 4;  // + r
        const bool diag = (s0 == q0);
        float pmax[4];
#pragma unroll
        for (int r = 0; r < 4; ++r) pmax[r] = -1e30f;
#pragma unroll
        for (int n = 0; n < 4; ++n) {
#pragma unroll
            for (int r = 0; r < 4; ++r) {
                float v = S[n][r] * 0.03125f;
                if (diag) {
                    int scol = s0 + n * 16 + l15;
                    if (scol > qrow + r) v = -1e30f;
                }
                S[n][r] = v;
                pmax[r] = fmaxf(pmax[r], v);
            }
        }
#pragma unroll
        for (int r = 0; r < 4; ++r) {
            float v = pmax[r];
            v = fmaxf(v, __shfl_xor(v, 1));
            v = fmaxf(v, __shfl_xor(v, 2));
            v = fmaxf(v, __shfl_xor(v, 4));
            v = fmaxf(v, __shfl_xor(v, 8));
            pmax[r] = v;
        }

        // ---- online softmax update ----
        float psum[4];
#pragma unroll
        for (int r = 0; r < 4; ++r) {
            float mnew = fmaxf(mrow[r], pmax[r]);
            float fr = __expf(mrow[r] - mnew);
            mrow[r] = mnew;
            srow[r] *= fr;
#pragma unroll
            for (int n = 0; n < 4; ++n) O[n][r] *= fr;
            psum[r] = 0.0f;
        }
#pragma unroll
        for (int n = 0; n < 4; ++n) {
#pragma unroll
            for (int r = 0; r < 4; ++r) {
                float p = __expf(S[n][r] - mrow[r]);
                psum[r] += p;
                Ps[wave][l4 * 4 + r][n * 16 + l15] = f2bf(p);
            }
        }
#pragma unroll
        for (int r = 0; r < 4; ++r) {
            float v = psum[r];
            v += __shfl_xor(v, 1);
            v += __shfl_xor(v, 2);
            v += __shfl_xor(v, 4);
            v += __shfl_xor(v, 8);
            srow[r] += v;
        }
        // wave-local: ensure our P writes landed before re-reading as A-frags
        asm volatile("s_waitcnt lgkmcnt(0)" ::: "memory");

        // ---- O += P V ----
        bf16x8 ap0 = *(const bf16x8*)&Ps[wave][l15][l4 * 8];
        bf16x8 ap1 = *(const bf16x8*)&Ps[wave][l15][32 + l4 * 8];
#pragma unroll
        for (int n = 0; n < 4; ++n) {
            bf16x8 bv0 = *(const bf16x8*)&Vt[n * 16 + l15][l4 * 8];
            bf16x8 bv1 = *(const bf16x8*)&Vt[n * 16 + l15][32 + l4 * 8];
            O[n] = __builtin_amdgcn_mfma_f32_16x16x32_bf16(ap0, bv0, O[n], 0, 0, 0);
            O[n] = __builtin_amdgcn_mfma_f32_16x16x32_bf16(ap1, bv1, O[n], 0, 0, 0);
        }
    }

    // ---- normalize + store bf16 to [B*T][1024] (concat heads) ----
#pragma unroll
    for (int r = 0; r < 4; ++r) {
        float inv = 1.0f / srow[r];
        int row = q0 + wave * 16 + l4 * 4 + r;
        size_t obase = ((size_t)b * T_ + row) * C_ + h * 64;
#pragma unroll
        for (int n = 0; n < 4; ++n)
            out[obase + n * 16 + l15] = f2bf(O[n][r] * inv);
    }
}

// ---------------------------------------------------------------------------
extern "C" void kernel_launch(void* const* d_in, const int* in_sizes, int n_in,
                              void* d_out, int out_size, void* d_ws, size_t ws_size,
                              hipStream_t stream) {
    const float* x     = (const float*)d_in[0];
    const float* wq    = (const float*)d_in[1];
    const float* wk    = (const float*)d_in[2];
    const float* wv    = (const float*)d_in[3];
    const float* wproj = (const float*)d_in[4];
    const float* bproj = (const float*)d_in[5];
    float* out = (float*)d_out;

    // workspace layout (shorts): wqkv_t | wproj_t | qkv | attn_out
    short* wqkv_t  = (short*)d_ws;                  // 3072*1024
    short* wproj_t = wqkv_t + 3072 * 1024;          // 1024*1024
    short* qkv_b   = wproj_t + 1024 * 1024;         // 8192*3072
    short* attn_b  = qkv_b + (size_t)8192 * 3072;   // 8192*1024
    // total = 75,497,472 bytes

    pack_wqkv<<<1536, 256, 0, stream>>>(wq, wk, wv, wqkv_t);
    pack_wproj<<<512, 256, 0, stream>>>(wproj, wproj_t);

    // QKV projection: [8192,1024] x [1024,3072]
    gemm_bf16<true, false><<<dim3(24, 64), 256, 0, stream>>>(
        x, wqkv_t, qkv_b, nullptr, 8192, 3072, 1024);

    // flash attention
    attn_kernel<<<dim3(32, 64), 256, 0, stream>>>(qkv_b, attn_b);

    // output projection: [8192,1024] x [1024,1024] + bias -> fp32 out
    gemm_bf16<false, true><<<dim3(8, 64), 256, 0, stream>>>(
        attn_b, wproj_t, out, bproj, 8192, 1024, 1024);
}